// Round 15
// baseline (259.927 us; speedup 1.0000x reference)
//
#include <hip/hip_runtime.h>

typedef __bf16 bf16;
typedef __bf16 bf16x4 __attribute__((ext_vector_type(4)));
typedef __bf16 bf16x8 __attribute__((ext_vector_type(8)));
typedef float  f32x4  __attribute__((ext_vector_type(4)));

#define AS1 __attribute__((address_space(1)))
#define AS3 __attribute__((address_space(3)))

__device__ __forceinline__ void gload_lds16(const void* g, void* l) {
    __builtin_amdgcn_global_load_lds((const AS1 void*)g, (AS3 void*)l, 16, 0, 0);
}

// bijective XCD swizzle: contiguous chunk of nwg/8 tiles per XCD (nwg%8==0)
__device__ __forceinline__ int xcd_swz(int wid, int nwg) {
    return (wid & 7) * (nwg >> 3) + (wid >> 3);
}

// ---------------- fused prep: cast X, transpose W's, concat bias -------------
__global__ __launch_bounds__(256) void prep(
    const float* __restrict__ X,  const float* __restrict__ Wq,
    const float* __restrict__ Wk, const float* __restrict__ Wv,
    const float* __restrict__ Wo, const float* __restrict__ bq,
    const float* __restrict__ bk, const float* __restrict__ bv,
    bf16* __restrict__ Xb, bf16* __restrict__ Wqkvt,
    bf16* __restrict__ Wot, float* __restrict__ bqkv)
{
    __shared__ float tile[32][33];
    int bid = blockIdx.x;
    if (bid < 8192) {                                   // cast X (float4 -> bf16x4)
        int i = bid * 256 + threadIdx.x;
        float4 v = ((const float4*)X)[i];
        bf16x4 o = { (bf16)v.x, (bf16)v.y, (bf16)v.z, (bf16)v.w };
        ((bf16x4*)Xb)[i] = o;
        return;
    }
    bid -= 8192;
    const float* src; bf16* dst; int R, C, bx, by;
    if (bid < 4096)      { src = Wq; dst = Wqkvt;                      R = 2048; C = 2048; bx = bid & 63; by = bid >> 6; }
    else if (bid < 4608) { int t = bid - 4096; src = Wk; dst = Wqkvt + (size_t)2048 * 2048; R = 2048; C = 256; bx = t & 7; by = t >> 3; }
    else if (bid < 5120) { int t = bid - 4608; src = Wv; dst = Wqkvt + (size_t)2304 * 2048; R = 2048; C = 256; bx = t & 7; by = t >> 3; }
    else if (bid < 9216) { int t = bid - 5120; src = Wo; dst = Wot;    R = 2048; C = 2048; bx = t & 63; by = t >> 6; }
    else {                                              // bias concat (10 blocks)
        int i = (bid - 9216) * 256 + threadIdx.x;
        if (i < 2048) bqkv[i] = bq[i];
        else if (i < 2304) bqkv[i] = bk[i - 2048];
        else if (i < 2560) bqkv[i] = bv[i - 2304];
        return;
    }
    int tx = threadIdx.x & 31, tg = threadIdx.x >> 5;
    int c0 = bx * 32, r0 = by * 32;
    #pragma unroll
    for (int j = tg; j < 32; j += 8)
        tile[j][tx] = src[(size_t)(r0 + j) * C + c0 + tx];
    __syncthreads();
    #pragma unroll
    for (int j = tg; j < 32; j += 8)
        dst[(size_t)(c0 + j) * R + r0 + tx] = (bf16)tile[tx][j];
}

// ---------------- GEMM: C[M][N] = (A[M][K] @ Bt[N][K]^T + bias) * scale -----
template<int OUTBF>
__global__ __launch_bounds__(256) void gemm_bt(
    const bf16* __restrict__ A, const bf16* __restrict__ Bt,
    const float* __restrict__ bias, void* __restrict__ Cv,
    int M, int N, int K, float scale)
{
    __shared__ bf16 As[128 * 32];
    __shared__ bf16 Bs[128 * 32];
    const int tid = threadIdx.x;
    const int l = tid & 63, w = tid >> 6;
    const int wm = w >> 1, wn = w & 1;

    const int gx = N >> 7, gy = M >> 7;
    const int idx = xcd_swz(blockIdx.x + gx * blockIdx.y, gx * gy);
    const size_t colBase = (size_t)(idx % gx) * 128;
    const size_t rowBase = (size_t)(idx / gx) * 128;

    f32x4 acc[4][4] = {};

    const int srow = l >> 2;
    const int schunk = (l & 3) ^ ((l >> 3) & 3);
    const int frow = l & 15;
    const int fswz = (frow >> 1) & 3;
    const int g = l >> 4;

    const bf16* Ag = A  + (rowBase + w * 32 + srow) * (size_t)K + schunk * 8;
    const bf16* Bg = Bt + (colBase + w * 32 + srow) * (size_t)K + schunk * 8;

    for (int k0 = 0; k0 < K; k0 += 32) {
        gload_lds16(Ag + k0,                  As + (w * 32) * 32);
        gload_lds16(Ag + 16 * (size_t)K + k0, As + (w * 32 + 16) * 32);
        gload_lds16(Bg + k0,                  Bs + (w * 32) * 32);
        gload_lds16(Bg + 16 * (size_t)K + k0, Bs + (w * 32 + 16) * 32);
        __syncthreads();

        bf16x8 af[4], bfr[4];
        #pragma unroll
        for (int mi = 0; mi < 4; ++mi)
            af[mi] = *(const bf16x8*)(As + (wm * 64 + mi * 16 + frow) * 32 + ((g ^ fswz) << 3));
        #pragma unroll
        for (int ni = 0; ni < 4; ++ni)
            bfr[ni] = *(const bf16x8*)(Bs + (wn * 64 + ni * 16 + frow) * 32 + ((g ^ fswz) << 3));
        #pragma unroll
        for (int mi = 0; mi < 4; ++mi)
            #pragma unroll
            for (int ni = 0; ni < 4; ++ni)
                acc[mi][ni] = __builtin_amdgcn_mfma_f32_16x16x32_bf16(af[mi], bfr[ni], acc[mi][ni], 0, 0, 0);
        __syncthreads();
    }

    const int cr = (l >> 4) * 4;
    const int cc = l & 15;
    #pragma unroll
    for (int ni = 0; ni < 4; ++ni) {
        const int col = (int)colBase + wn * 64 + ni * 16 + cc;
        const float bv = bias[col];
        #pragma unroll
        for (int mi = 0; mi < 4; ++mi) {
            #pragma unroll
            for (int r = 0; r < 4; ++r) {
                const size_t row = rowBase + wm * 64 + mi * 16 + cr + r;
                float v = (acc[mi][ni][r] + bv) * scale;
                if (OUTBF) ((bf16*)Cv)[row * N + col] = (bf16)v;
                else       ((float*)Cv)[row * N + col] = v;
            }
        }
    }
}

// ---------------- fused QKV projection GEMM ----------------------------------
__global__ __launch_bounds__(256) void gemm_qkv(
    const bf16* __restrict__ A, const bf16* __restrict__ Bt,
    const float* __restrict__ bias, bf16* __restrict__ Qb, bf16* __restrict__ Kb,
    bf16* __restrict__ VT, float qscale)
{
    constexpr int K = 2048;
    __shared__ bf16 As[128 * 32];
    __shared__ bf16 Bs[128 * 32];
    const int tid = threadIdx.x;
    const int l = tid & 63, w = tid >> 6;
    const int wm = w >> 1, wn = w & 1;

    const int idx = xcd_swz(blockIdx.x + 20 * blockIdx.y, 640);
    const size_t colBase = (size_t)(idx % 20) * 128;
    const size_t rowBase = (size_t)(idx / 20) * 128;

    f32x4 acc[4][4] = {};

    const int srow = l >> 2;
    const int schunk = (l & 3) ^ ((l >> 3) & 3);
    const int frow = l & 15;
    const int fswz = (frow >> 1) & 3;
    const int g = l >> 4;

    const bf16* Ag = A  + (rowBase + w * 32 + srow) * (size_t)K + schunk * 8;
    const bf16* Bg = Bt + (colBase + w * 32 + srow) * (size_t)K + schunk * 8;

    for (int k0 = 0; k0 < K; k0 += 32) {
        gload_lds16(Ag + k0,                  As + (w * 32) * 32);
        gload_lds16(Ag + 16 * (size_t)K + k0, As + (w * 32 + 16) * 32);
        gload_lds16(Bg + k0,                  Bs + (w * 32) * 32);
        gload_lds16(Bg + 16 * (size_t)K + k0, Bs + (w * 32 + 16) * 32);
        __syncthreads();

        bf16x8 af[4], bfr[4];
        #pragma unroll
        for (int mi = 0; mi < 4; ++mi)
            af[mi] = *(const bf16x8*)(As + (wm * 64 + mi * 16 + frow) * 32 + ((g ^ fswz) << 3));
        #pragma unroll
        for (int ni = 0; ni < 4; ++ni)
            bfr[ni] = *(const bf16x8*)(Bs + (wn * 64 + ni * 16 + frow) * 32 + ((g ^ fswz) << 3));
        #pragma unroll
        for (int mi = 0; mi < 4; ++mi)
            #pragma unroll
            for (int ni = 0; ni < 4; ++ni)
                acc[mi][ni] = __builtin_amdgcn_mfma_f32_16x16x32_bf16(af[mi], bfr[ni], acc[mi][ni], 0, 0, 0);
        __syncthreads();
    }

    const int cr = (l >> 4) * 4;
    const int cc = l & 15;
    const int cb = (int)colBase;
    #pragma unroll
    for (int ni = 0; ni < 4; ++ni) {
        const int col = cb + wn * 64 + ni * 16 + cc;
        const float bv = bias[col];
        if (cb < 2048) {                       // Q (scaled)
            #pragma unroll
            for (int mi = 0; mi < 4; ++mi)
                #pragma unroll
                for (int r = 0; r < 4; ++r) {
                    const size_t row = rowBase + wm * 64 + mi * 16 + cr + r;
                    Qb[row * 2048 + col] = (bf16)((acc[mi][ni][r] + bv) * qscale);
                }
        } else if (cb < 2304) {                // K -> Kbuf[4096][256]
            #pragma unroll
            for (int mi = 0; mi < 4; ++mi)
                #pragma unroll
                for (int r = 0; r < 4; ++r) {
                    const size_t row = rowBase + wm * 64 + mi * 16 + cr + r;
                    Kb[row * 256 + (col - 2048)] = (bf16)(acc[mi][ni][r] + bv);
                }
        } else {                               // V -> pi-permuted VT
            const int vcol = col - 2304;
            const int kvh = vcol >> 7, d = vcol & 127;
            #pragma unroll
            for (int mi = 0; mi < 4; ++mi) {
                const size_t row0 = rowBase + wm * 64 + mi * 16 + cr;   // %4 == 0
                const int bb = (int)(row0 >> 11);
                const int s  = (int)(row0 & 2047);
                const int tile = s >> 6, sp = s & 63;
                const int slot = (sp & 35) | ((sp & 8) << 1) | ((sp & 4) << 1) | ((sp & 16) >> 2);
                bf16x4 v4 = { (bf16)(acc[mi][ni][0] + bv), (bf16)(acc[mi][ni][1] + bv),
                              (bf16)(acc[mi][ni][2] + bv), (bf16)(acc[mi][ni][3] + bv) };
                *(bf16x4*)(VT + ((size_t)((bb * 2 + kvh) * 128 + d)) * 2048 + tile * 64 + slot) = v4;
            }
        }
    }
}

// ---------------- fused flash attention -------------------------------------
// grid 512 blocks (2/CU), 256 threads (4 waves x 32 q-rows), XCD-swizzled.
// K double-buffered in 32KB static LDS; V read DIRECTLY from global VT into
// registers (L1-resident: 16KB tile shared by 8 waves of 2 same-(h,b) blocks),
// T15-lagged so V(t) loads issue after PV(t-1) frees the regs and are consumed
// a full tile later. Halves LDS read demand (the measured bottleneck).
__global__ __launch_bounds__(256, 2) void attn_fwd(
    const bf16* __restrict__ Q, const bf16* __restrict__ Kb,
    const bf16* __restrict__ VT, bf16* __restrict__ O)
{
    constexpr int S = 2048;
    constexpr int NT = S / 64;
    __shared__ bf16 Ks[2 * 64 * 128];   // 32 KB, K only

    const int tid = threadIdx.x;
    const int l = tid & 63, w = tid >> 6;           // w in 0..3
    const int idx = xcd_swz(blockIdx.x + 16 * blockIdx.y + 256 * blockIdx.z, 512);
    const int qt = idx & 15, h = (idx >> 4) & 15, b = idx >> 8;
    const int kvh = h >> 3;
    const int lg = l >> 4, ll = l & 15;
    const int eh = (ll >> 2) & 1;

    // Q fragments, two 16-row groups: A = rows qt*128+w*32+ll, B = +16
    bf16x8 qfA[4], qfB[4];
    {
        const bf16* qpA = Q + ((size_t)(b * S + qt * 128 + w * 32 + ll)) * 2048 + h * 128 + lg * 8;
        const bf16* qpB = qpA + 16 * 2048;
        #pragma unroll
        for (int j = 0; j < 4; ++j) {
            qfA[j] = *(const bf16x8*)(qpA + (j << 5));
            qfB[j] = *(const bf16x8*)(qpB + (j << 5));
        }
    }

    const bf16* Kg  = Kb + (size_t)b * S * 256 + kvh * 128;
    const bf16* VTg = VT + ((size_t)(b * 2 + kvh) * 128) * S;

    // K staging (4 waves): rows w*16+{0..15}, source-side XOR chunk swizzle
    const bf16* kgA = Kg + (size_t)(w * 16 + lg) * 256 + (ll ^ lg) * 8;
    const bf16* kgB = Kg + (size_t)(w * 16 + 4 + lg) * 256 + (ll ^ (4 + lg)) * 8;
    const int kdA = (w * 16) * 128;
    const int kdB = (w * 16 + 4) * 128;

    // K fragment-read bases (even/odd absorb the eh XOR term)
    const int swz8 = (lg ^ (ll & 3)) << 3;
    const int kbE = ll * 128 + swz8 + eh * 32;
    const int kbO = ll * 128 + swz8 + (1 - eh) * 32;

    // V direct-from-global base: row = nf*16+ll, in-row = t*64 + c*32 + lg*8
    const bf16* vgB = VTg + (size_t)ll * S + lg * 8;

    bf16x8 vones;
    #pragma unroll
    for (int e = 0; e < 8; ++e) vones[e] = (bf16)1.0f;

    f32x4 ofA[8] = {}, ofB[8] = {};
    f32x4 olA = {}, olB = {};
    bf16x8 pA0, pA1, pB0, pB1;    // P of tile t-1 (pending PV)
    bf16x8 vr0[8], vr1[8];        // V of tile t-1 (pending PV), phases c=0/1

#define STAGEK(koff, kbuf)                                                      \
    {                                                                           \
        gload_lds16(kgA + (koff),        Ks + (kbuf) * 8192 + kdA);             \
        gload_lds16(kgB + (koff),        Ks + (kbuf) * 8192 + kdB);             \
        gload_lds16(kgA + (koff) + 2048, Ks + (kbuf) * 8192 + kdA + 1024);      \
        gload_lds16(kgB + (koff) + 2048, Ks + (kbuf) * 8192 + kdB + 1024);      \
    }

    // ---- prologue: stage K tile 0 ----
    STAGEK(0, 0)
    __syncthreads();

    for (int t = 0; t < NT; ++t) {
        const int buf = t & 1;
        if (t + 1 < NT) STAGEK((size_t)(t + 1) * 64 * 256, buf ^ 1)

        // ---- QK^T(t), both q-groups share each K fragment ----
        const bf16* kE = Ks + buf * 8192 + kbE;
        const bf16* kO = Ks + buf * 8192 + kbO;
        f32x4 scA[4] = {}, scB[4] = {};
        __builtin_amdgcn_s_setprio(1);
        #pragma unroll
        for (int ni = 0; ni < 4; ++ni) {
            bf16x8 k0f = *(const bf16x8*)(kE + ni * 2048);
            scA[ni] = __builtin_amdgcn_mfma_f32_16x16x32_bf16(k0f, qfA[0], scA[ni], 0, 0, 0);
            scB[ni] = __builtin_amdgcn_mfma_f32_16x16x32_bf16(k0f, qfB[0], scB[ni], 0, 0, 0);
            bf16x8 k1f = *(const bf16x8*)(kO + ni * 2048);
            scA[ni] = __builtin_amdgcn_mfma_f32_16x16x32_bf16(k1f, qfA[1], scA[ni], 0, 0, 0);
            scB[ni] = __builtin_amdgcn_mfma_f32_16x16x32_bf16(k1f, qfB[1], scB[ni], 0, 0, 0);
            bf16x8 k2f = *(const bf16x8*)(kE + ni * 2048 + 64);
            scA[ni] = __builtin_amdgcn_mfma_f32_16x16x32_bf16(k2f, qfA[2], scA[ni], 0, 0, 0);
            scB[ni] = __builtin_amdgcn_mfma_f32_16x16x32_bf16(k2f, qfB[2], scB[ni], 0, 0, 0);
            bf16x8 k3f = *(const bf16x8*)(kO + ni * 2048 + 64);
            scA[ni] = __builtin_amdgcn_mfma_f32_16x16x32_bf16(k3f, qfA[3], scA[ni], 0, 0, 0);
            scB[ni] = __builtin_amdgcn_mfma_f32_16x16x32_bf16(k3f, qfB[3], scB[ni], 0, 0, 0);
        }
        __builtin_amdgcn_s_setprio(0);

        // ---- PV(t-1) from vr registers (V loaded last iteration) ----
        if (t > 0) {
            __builtin_amdgcn_s_setprio(1);
            olA = __builtin_amdgcn_mfma_f32_16x16x32_bf16(pA0, vones, olA, 0, 0, 0);
            olB = __builtin_amdgcn_mfma_f32_16x16x32_bf16(pB0, vones, olB, 0, 0, 0);
            #pragma unroll
            for (int nf = 0; nf < 8; ++nf) {
                ofA[nf] = __builtin_amdgcn_mfma_f32_16x16x32_bf16(pA0, vr0[nf], ofA[nf], 0, 0, 0);
                ofB[nf] = __builtin_amdgcn_mfma_f32_16x16x32_bf16(pB0, vr0[nf], ofB[nf], 0, 0, 0);
            }
            olA = __builtin_amdgcn_mfma_f32_16x16x32_bf16(pA1, vones, olA, 0, 0, 0);
            olB = __builtin_amdgcn_mfma_f32_16x16x32_bf16(pB1, vones, olB, 0, 0, 0);
            #pragma unroll
            for (int nf = 0; nf < 8; ++nf) {
                ofA[nf] = __builtin_amdgcn_mfma_f32_16x16x32_bf16(pA1, vr1[nf], ofA[nf], 0, 0, 0);
                ofB[nf] = __builtin_amdgcn_mfma_f32_16x16x32_bf16(pB1, vr1[nf], ofB[nf], 0, 0, 0);
            }
            __builtin_amdgcn_s_setprio(0);
        }

        // ---- issue V(t) loads into vr (consumed in PV at tile t+1) ----
        {
            const bf16* vsrc = vgB + t * 64;
            #pragma unroll
            for (int nf = 0; nf < 8; ++nf) {
                vr0[nf] = *(const bf16x8*)(vsrc + (size_t)nf * 32768);
                vr1[nf] = *(const bf16x8*)(vsrc + (size_t)nf * 32768 + 32);
            }
        }

        // ---- exp2(t) + pack (VALU; overlaps PV MFMAs / V-load latency) ----
        float pa[4][4], pb[4][4];
        #pragma unroll
        for (int ni = 0; ni < 4; ++ni)
            #pragma unroll
            for (int r = 0; r < 4; ++r) {
                pa[ni][r] = __builtin_exp2f(scA[ni][r]);
                pb[ni][r] = __builtin_exp2f(scB[ni][r]);
            }
        #pragma unroll
        for (int e = 0; e < 8; ++e) {
            pA0[e] = (bf16)pa[(e >> 2)][e & 3];
            pA1[e] = (bf16)pa[2 + (e >> 2)][e & 3];
            pB0[e] = (bf16)pb[(e >> 2)][e & 3];
            pB1[e] = (bf16)pb[2 + (e >> 2)][e & 3];
        }

        __syncthreads();   // K stage(t+1) drained; all waves done with Ks[buf]
    }

    // ---- epilogue: PV(NT-1) ----
    {
        olA = __builtin_amdgcn_mfma_f32_16x16x32_bf16(pA0, vones, olA, 0, 0, 0);
        olB = __builtin_amdgcn_mfma_f32_16x16x32_bf16(pB0, vones, olB, 0, 0, 0);
        #pragma unroll
        for (int nf = 0; nf < 8; ++nf) {
            ofA[nf] = __builtin_amdgcn_mfma_f32_16x16x32_bf16(pA0, vr0[nf], ofA[nf], 0, 0, 0);
            ofB[nf] = __builtin_amdgcn_mfma_f32_16x16x32_bf16(pB0, vr0[nf], ofB[nf], 0, 0, 0);
        }
        olA = __builtin_amdgcn_mfma_f32_16x16x32_bf16(pA1, vones, olA, 0, 0, 0);
        olB = __builtin_amdgcn_mfma_f32_16x16x32_bf16(pB1, vones, olB, 0, 0, 0);
        #pragma unroll
        for (int nf = 0; nf < 8; ++nf) {
            ofA[nf] = __builtin_amdgcn_mfma_f32_16x16x32_bf16(pA1, vr1[nf], ofA[nf], 0, 0, 0);
            ofB[nf] = __builtin_amdgcn_mfma_f32_16x16x32_bf16(pB1, vr1[nf], ofB[nf], 0, 0, 0);
        }
    }

    // ---- normalize + store, both groups ----
    #pragma unroll
    for (int r = 0; r < 4; ++r) {
        float invA = 1.0f / olA[r];
        float invB = 1.0f / olB[r];
        size_t rowA = (size_t)(b * S + qt * 128 + w * 32 + lg * 4 + r);
        bf16* opA = O + rowA * 2048 + h * 128 + ll;
        bf16* opB = opA + 16 * 2048;
        #pragma unroll
        for (int nf = 0; nf < 8; ++nf) {
            opA[nf * 16] = (bf16)(ofA[nf][r] * invA);
            opB[nf * 16] = (bf16)(ofB[nf][r] * invB);
        }
    }
#undef STAGEK
}

// ---------------- launcher ---------------------------------------------------
extern "C" void kernel_launch(void* const* d_in, const int* in_sizes, int n_in,
                              void* d_out, int out_size, void* d_ws, size_t ws_size,
                              hipStream_t stream)
{
    const float* X  = (const float*)d_in[0];
    const float* Wq = (const float*)d_in[1];
    const float* bq = (const float*)d_in[2];
    const float* Wk = (const float*)d_in[3];
    const float* bk = (const float*)d_in[4];
    const float* Wv = (const float*)d_in[5];
    const float* bv = (const float*)d_in[6];
    const float* Wo = (const float*)d_in[7];
    const float* bo = (const float*)d_in[8];
    float* out = (float*)d_out;

    // workspace layout (bf16 elements)
    bf16* p = (bf16*)d_ws;
    bf16* Xb    = p; p += 8388608;   // [4096][2048] X bf16 (reused as attn output)
    bf16* Qb    = p; p += 8388608;   // [4096][2048]
    bf16* Kbuf  = p; p += 1048576;   // [4096][256]
    bf16* VTb   = p; p += 1048576;   // [512][2048] : pi-permuted V^T
    bf16* Wqkvt = p; p += 5242880;   // [2560][2048]: Wq^T | Wk^T | Wv^T
    bf16* Wot   = p; p += 4194304;   // [2048][2048]
    float* bqkv = (float*)p; p += 5120;  // 2560 floats
    bf16* Oattn = Xb;                // alias: X dead after QKV projection

    // 1/sqrt(128) * log2(e)  (exp2-domain softmax)
    const float qscale = 0.12751744f;

    prep<<<17418, 256, 0, stream>>>(X, Wq, Wk, Wv, Wo, bq, bk, bv,
                                    Xb, Wqkvt, Wot, bqkv);

    gemm_qkv<<<dim3(20, 32), 256, 0, stream>>>(Xb, Wqkvt, bqkv, Qb, Kbuf, VTb, qscale);

    attn_fwd<<<dim3(16, 16, 2), 256, 0, stream>>>(Qb, Kbuf, VTb, Oattn);

    gemm_bt<0><<<dim3(16, 32), 256, 0, stream>>>(Oattn, Wot, bo, out, 4096, 2048, 2048, 1.0f);
}

// Round 16
// 193.949 us; speedup vs baseline: 1.3402x; 1.3402x over previous
//
#include <hip/hip_runtime.h>

typedef __bf16 bf16;
typedef __bf16 bf16x4 __attribute__((ext_vector_type(4)));
typedef __bf16 bf16x8 __attribute__((ext_vector_type(8)));
typedef float  f32x4  __attribute__((ext_vector_type(4)));

#define AS1 __attribute__((address_space(1)))
#define AS3 __attribute__((address_space(3)))

__device__ __forceinline__ void gload_lds16(const void* g, void* l) {
    __builtin_amdgcn_global_load_lds((const AS1 void*)g, (AS3 void*)l, 16, 0, 0);
}

// bijective XCD swizzle: contiguous chunk of nwg/8 tiles per XCD (nwg%8==0)
__device__ __forceinline__ int xcd_swz(int wid, int nwg) {
    return (wid & 7) * (nwg >> 3) + (wid >> 3);
}

// ---------------- fused prep: cast X, transpose W's, concat bias -------------
__global__ __launch_bounds__(256) void prep(
    const float* __restrict__ X,  const float* __restrict__ Wq,
    const float* __restrict__ Wk, const float* __restrict__ Wv,
    const float* __restrict__ Wo, const float* __restrict__ bq,
    const float* __restrict__ bk, const float* __restrict__ bv,
    bf16* __restrict__ Xb, bf16* __restrict__ Wqkvt,
    bf16* __restrict__ Wot, float* __restrict__ bqkv)
{
    __shared__ float tile[32][33];
    int bid = blockIdx.x;
    if (bid < 8192) {                                   // cast X (float4 -> bf16x4)
        int i = bid * 256 + threadIdx.x;
        float4 v = ((const float4*)X)[i];
        bf16x4 o = { (bf16)v.x, (bf16)v.y, (bf16)v.z, (bf16)v.w };
        ((bf16x4*)Xb)[i] = o;
        return;
    }
    bid -= 8192;
    const float* src; bf16* dst; int R, C, bx, by;
    if (bid < 4096)      { src = Wq; dst = Wqkvt;                      R = 2048; C = 2048; bx = bid & 63; by = bid >> 6; }
    else if (bid < 4608) { int t = bid - 4096; src = Wk; dst = Wqkvt + (size_t)2048 * 2048; R = 2048; C = 256; bx = t & 7; by = t >> 3; }
    else if (bid < 5120) { int t = bid - 4608; src = Wv; dst = Wqkvt + (size_t)2304 * 2048; R = 2048; C = 256; bx = t & 7; by = t >> 3; }
    else if (bid < 9216) { int t = bid - 5120; src = Wo; dst = Wot;    R = 2048; C = 2048; bx = t & 63; by = t >> 6; }
    else {                                              // bias concat (10 blocks)
        int i = (bid - 9216) * 256 + threadIdx.x;
        if (i < 2048) bqkv[i] = bq[i];
        else if (i < 2304) bqkv[i] = bk[i - 2048];
        else if (i < 2560) bqkv[i] = bv[i - 2304];
        return;
    }
    int tx = threadIdx.x & 31, tg = threadIdx.x >> 5;
    int c0 = bx * 32, r0 = by * 32;
    #pragma unroll
    for (int j = tg; j < 32; j += 8)
        tile[j][tx] = src[(size_t)(r0 + j) * C + c0 + tx];
    __syncthreads();
    #pragma unroll
    for (int j = tg; j < 32; j += 8)
        dst[(size_t)(c0 + j) * R + r0 + tx] = (bf16)tile[tx][j];
}

// ---------------- GEMM: C[M][N] = (A[M][K] @ Bt[N][K]^T + bias) * scale -----
template<int OUTBF>
__global__ __launch_bounds__(256) void gemm_bt(
    const bf16* __restrict__ A, const bf16* __restrict__ Bt,
    const float* __restrict__ bias, void* __restrict__ Cv,
    int M, int N, int K, float scale)
{
    __shared__ bf16 As[128 * 32];
    __shared__ bf16 Bs[128 * 32];
    const int tid = threadIdx.x;
    const int l = tid & 63, w = tid >> 6;
    const int wm = w >> 1, wn = w & 1;

    // XCD-swizzled tile mapping (contiguous tile chunk per XCD)
    const int gx = N >> 7, gy = M >> 7;
    const int idx = xcd_swz(blockIdx.x + gx * blockIdx.y, gx * gy);
    const size_t colBase = (size_t)(idx % gx) * 128;
    const size_t rowBase = (size_t)(idx / gx) * 128;

    f32x4 acc[4][4] = {};

    const int srow = l >> 2;
    const int schunk = (l & 3) ^ ((l >> 3) & 3);
    const int frow = l & 15;
    const int fswz = (frow >> 1) & 3;
    const int g = l >> 4;

    const bf16* Ag = A  + (rowBase + w * 32 + srow) * (size_t)K + schunk * 8;
    const bf16* Bg = Bt + (colBase + w * 32 + srow) * (size_t)K + schunk * 8;

    for (int k0 = 0; k0 < K; k0 += 32) {
        gload_lds16(Ag + k0,                  As + (w * 32) * 32);
        gload_lds16(Ag + 16 * (size_t)K + k0, As + (w * 32 + 16) * 32);
        gload_lds16(Bg + k0,                  Bs + (w * 32) * 32);
        gload_lds16(Bg + 16 * (size_t)K + k0, Bs + (w * 32 + 16) * 32);
        __syncthreads();

        bf16x8 af[4], bfr[4];
        #pragma unroll
        for (int mi = 0; mi < 4; ++mi)
            af[mi] = *(const bf16x8*)(As + (wm * 64 + mi * 16 + frow) * 32 + ((g ^ fswz) << 3));
        #pragma unroll
        for (int ni = 0; ni < 4; ++ni)
            bfr[ni] = *(const bf16x8*)(Bs + (wn * 64 + ni * 16 + frow) * 32 + ((g ^ fswz) << 3));
        #pragma unroll
        for (int mi = 0; mi < 4; ++mi)
            #pragma unroll
            for (int ni = 0; ni < 4; ++ni)
                acc[mi][ni] = __builtin_amdgcn_mfma_f32_16x16x32_bf16(af[mi], bfr[ni], acc[mi][ni], 0, 0, 0);
        __syncthreads();
    }

    const int cr = (l >> 4) * 4;
    const int cc = l & 15;
    #pragma unroll
    for (int ni = 0; ni < 4; ++ni) {
        const int col = (int)colBase + wn * 64 + ni * 16 + cc;
        const float bv = bias[col];
        #pragma unroll
        for (int mi = 0; mi < 4; ++mi) {
            #pragma unroll
            for (int r = 0; r < 4; ++r) {
                const size_t row = rowBase + wm * 64 + mi * 16 + cr + r;
                float v = (acc[mi][ni][r] + bv) * scale;
                if (OUTBF) ((bf16*)Cv)[row * N + col] = (bf16)v;
                else       ((float*)Cv)[row * N + col] = v;
            }
        }
    }
}

// ---------------- fused QKV projection GEMM ----------------------------------
// cols<2048: Qb (x qscale) | cols 2048..2303: Kbuf[4096][256]
// cols 2304..2559: V scattered directly into pi-permuted VT[(b*2+kvh)*128+d][2048]
__global__ __launch_bounds__(256) void gemm_qkv(
    const bf16* __restrict__ A, const bf16* __restrict__ Bt,
    const float* __restrict__ bias, bf16* __restrict__ Qb, bf16* __restrict__ Kb,
    bf16* __restrict__ VT, float qscale)
{
    constexpr int K = 2048;
    __shared__ bf16 As[128 * 32];
    __shared__ bf16 Bs[128 * 32];
    const int tid = threadIdx.x;
    const int l = tid & 63, w = tid >> 6;
    const int wm = w >> 1, wn = w & 1;

    // XCD-swizzled tile mapping (grid 20 x 32 = 640 tiles, 80 per XCD)
    const int idx = xcd_swz(blockIdx.x + 20 * blockIdx.y, 640);
    const size_t colBase = (size_t)(idx % 20) * 128;
    const size_t rowBase = (size_t)(idx / 20) * 128;

    f32x4 acc[4][4] = {};

    const int srow = l >> 2;
    const int schunk = (l & 3) ^ ((l >> 3) & 3);
    const int frow = l & 15;
    const int fswz = (frow >> 1) & 3;
    const int g = l >> 4;

    const bf16* Ag = A  + (rowBase + w * 32 + srow) * (size_t)K + schunk * 8;
    const bf16* Bg = Bt + (colBase + w * 32 + srow) * (size_t)K + schunk * 8;

    for (int k0 = 0; k0 < K; k0 += 32) {
        gload_lds16(Ag + k0,                  As + (w * 32) * 32);
        gload_lds16(Ag + 16 * (size_t)K + k0, As + (w * 32 + 16) * 32);
        gload_lds16(Bg + k0,                  Bs + (w * 32) * 32);
        gload_lds16(Bg + 16 * (size_t)K + k0, Bs + (w * 32 + 16) * 32);
        __syncthreads();

        bf16x8 af[4], bfr[4];
        #pragma unroll
        for (int mi = 0; mi < 4; ++mi)
            af[mi] = *(const bf16x8*)(As + (wm * 64 + mi * 16 + frow) * 32 + ((g ^ fswz) << 3));
        #pragma unroll
        for (int ni = 0; ni < 4; ++ni)
            bfr[ni] = *(const bf16x8*)(Bs + (wn * 64 + ni * 16 + frow) * 32 + ((g ^ fswz) << 3));
        #pragma unroll
        for (int mi = 0; mi < 4; ++mi)
            #pragma unroll
            for (int ni = 0; ni < 4; ++ni)
                acc[mi][ni] = __builtin_amdgcn_mfma_f32_16x16x32_bf16(af[mi], bfr[ni], acc[mi][ni], 0, 0, 0);
        __syncthreads();
    }

    const int cr = (l >> 4) * 4;
    const int cc = l & 15;
    const int cb = (int)colBase;
    #pragma unroll
    for (int ni = 0; ni < 4; ++ni) {
        const int col = cb + wn * 64 + ni * 16 + cc;
        const float bv = bias[col];
        if (cb < 2048) {                       // Q (scaled)
            #pragma unroll
            for (int mi = 0; mi < 4; ++mi)
                #pragma unroll
                for (int r = 0; r < 4; ++r) {
                    const size_t row = rowBase + wm * 64 + mi * 16 + cr + r;
                    Qb[row * 2048 + col] = (bf16)((acc[mi][ni][r] + bv) * qscale);
                }
        } else if (cb < 2304) {                // K -> Kbuf[4096][256]
            #pragma unroll
            for (int mi = 0; mi < 4; ++mi)
                #pragma unroll
                for (int r = 0; r < 4; ++r) {
                    const size_t row = rowBase + wm * 64 + mi * 16 + cr + r;
                    Kb[row * 256 + (col - 2048)] = (bf16)(acc[mi][ni][r] + bv);
                }
        } else {                               // V -> pi-permuted VT
            const int vcol = col - 2304;
            const int kvh = vcol >> 7, d = vcol & 127;
            #pragma unroll
            for (int mi = 0; mi < 4; ++mi) {
                const size_t row0 = rowBase + wm * 64 + mi * 16 + cr;   // %4 == 0
                const int bb = (int)(row0 >> 11);
                const int s  = (int)(row0 & 2047);
                const int tile = s >> 6, sp = s & 63;
                // slot = k5<<5 | k3<<4 | k2<<3 | k4<<2 | k1<<1 | k0
                const int slot = (sp & 35) | ((sp & 8) << 1) | ((sp & 4) << 1) | ((sp & 16) >> 2);
                bf16x4 v4 = { (bf16)(acc[mi][ni][0] + bv), (bf16)(acc[mi][ni][1] + bv),
                              (bf16)(acc[mi][ni][2] + bv), (bf16)(acc[mi][ni][3] + bv) };
                *(bf16x4*)(VT + ((size_t)((bb * 2 + kvh) * 128 + d)) * 2048 + tile * 64 + slot) = v4;
            }
        }
    }
}

// ---------------- fused flash attention -------------------------------------
// grid 512 blocks (2/CU), 256 threads (4 waves x 32 q-rows), XCD-swizzled so
// each XCD's blocks share K/V panels in its L2. KVBLK=64, dbuf K + tri-buf V in
// 80KB dynamic LDS, T15 2-deep PV pipeline, ones-column row-sum, no-max exp2.
__global__ __launch_bounds__(256, 2) void attn_fwd(
    const bf16* __restrict__ Q, const bf16* __restrict__ Kb,
    const bf16* __restrict__ VT, bf16* __restrict__ O)
{
    constexpr int S = 2048;
    constexpr int NT = S / 64;
    extern __shared__ bf16 smem[];
    bf16* Ks = smem;              // [2][64*128]
    bf16* Vs = smem + 16384;      // [3][128*64]

    const int tid = threadIdx.x;
    const int l = tid & 63, w = tid >> 6;           // w in 0..3
    // XCD-swizzled (qt,h,b): 64 contiguous tiles (4 heads' worth) per XCD
    const int idx = xcd_swz(blockIdx.x + 16 * blockIdx.y + 256 * blockIdx.z, 512);
    const int qt = idx & 15, h = (idx >> 4) & 15, b = idx >> 8;
    const int kvh = h >> 3;
    const int lg = l >> 4, ll = l & 15;
    const int eh = (ll >> 2) & 1;

    // Q fragments, two 16-row groups: A = rows qt*128+w*32+ll, B = +16
    bf16x8 qfA[4], qfB[4];
    {
        const bf16* qpA = Q + ((size_t)(b * S + qt * 128 + w * 32 + ll)) * 2048 + h * 128 + lg * 8;
        const bf16* qpB = qpA + 16 * 2048;
        #pragma unroll
        for (int j = 0; j < 4; ++j) {
            qfA[j] = *(const bf16x8*)(qpA + (j << 5));
            qfB[j] = *(const bf16x8*)(qpB + (j << 5));
        }
    }

    const bf16* Kg  = Kb + (size_t)b * S * 256 + kvh * 128;
    const bf16* VTg = VT + ((size_t)(b * 2 + kvh) * 128) * S;

    // staging (4 waves): K rows w*16+{0..15}, V d-rows w*32+{0..31}
    const bf16* kgA = Kg + (size_t)(w * 16 + lg) * 256 + (ll ^ lg) * 8;
    const bf16* kgB = Kg + (size_t)(w * 16 + 4 + lg) * 256 + (ll ^ (4 + lg)) * 8;
    const bf16* vgA = VTg + (size_t)(w * 32 + (l >> 3)) * S + (((l & 7) ^ ((l >> 3) & 7)) << 3);
    const int kdA = (w * 16) * 128;       // wave's K region [w*2048, +2048)
    const int kdB = (w * 16 + 4) * 128;
    const int vdA = w * 2048;             // wave's V region [w*2048, +2048)

    // fragment-read bases (even/odd absorb the eh XOR term)
    const int swz8 = (lg ^ (ll & 3)) << 3;
    const int kbE = ll * 128 + swz8 + eh * 32;
    const int kbO = ll * 128 + swz8 + (1 - eh) * 32;
    const int vbE = ll * 64 + swz8 + eh * 32;
    const int vbO = ll * 64 + swz8 + (1 - eh) * 32;

    bf16x8 vones;
    #pragma unroll
    for (int e = 0; e < 8; ++e) vones[e] = (bf16)1.0f;

    f32x4 ofA[8] = {}, ofB[8] = {};
    f32x4 olA = {}, olB = {};
    bf16x8 pA0, pA1, pB0, pB1;    // P of tile t-1 (pending PV), both groups

#define STAGE(koff, vroff, kbuf, vslot)                                   \
    {                                                                     \
        gload_lds16(kgA + (koff),             Ks + (kbuf) * 8192 + kdA);  \
        gload_lds16(kgB + (koff),             Ks + (kbuf) * 8192 + kdB);  \
        gload_lds16(kgA + (koff) + 2048,      Ks + (kbuf) * 8192 + kdA + 1024); \
        gload_lds16(kgB + (koff) + 2048,      Ks + (kbuf) * 8192 + kdB + 1024); \
        gload_lds16(vgA + (vroff),            Vs + (vslot) * 8192 + vdA);       \
        gload_lds16(vgA + (vroff) + 8  * S,   Vs + (vslot) * 8192 + vdA + 512); \
        gload_lds16(vgA + (vroff) + 16 * S,   Vs + (vslot) * 8192 + vdA + 1024);\
        gload_lds16(vgA + (vroff) + 24 * S,   Vs + (vslot) * 8192 + vdA + 1536);\
    }

    // ---- prologue: stage tile 0 (K buf0, V slot0) ----
    STAGE(0, 0, 0, 0)
    __syncthreads();

    int sP = 2, sC = 0, sN = 1;   // V slot rotation (prev, cur, next)
    for (int t = 0; t < NT; ++t) {
        const int buf = t & 1;
        if (t + 1 < NT) {
            const size_t ko = (size_t)(t + 1) * 64 * 256;
            const int    vo = (t + 1) * 64;
            STAGE(ko, vo, buf ^ 1, sN)
        }

        // ---- QK^T(t), both q-groups share each K fragment ----
        const bf16* kE = Ks + buf * 8192 + kbE;
        const bf16* kO = Ks + buf * 8192 + kbO;
        f32x4 scA[4] = {}, scB[4] = {};
        __builtin_amdgcn_s_setprio(1);
        #pragma unroll
        for (int ni = 0; ni < 4; ++ni) {
            bf16x8 k0f = *(const bf16x8*)(kE + ni * 2048);
            scA[ni] = __builtin_amdgcn_mfma_f32_16x16x32_bf16(k0f, qfA[0], scA[ni], 0, 0, 0);
            scB[ni] = __builtin_amdgcn_mfma_f32_16x16x32_bf16(k0f, qfB[0], scB[ni], 0, 0, 0);
            bf16x8 k1f = *(const bf16x8*)(kO + ni * 2048);
            scA[ni] = __builtin_amdgcn_mfma_f32_16x16x32_bf16(k1f, qfA[1], scA[ni], 0, 0, 0);
            scB[ni] = __builtin_amdgcn_mfma_f32_16x16x32_bf16(k1f, qfB[1], scB[ni], 0, 0, 0);
            bf16x8 k2f = *(const bf16x8*)(kE + ni * 2048 + 64);
            scA[ni] = __builtin_amdgcn_mfma_f32_16x16x32_bf16(k2f, qfA[2], scA[ni], 0, 0, 0);
            scB[ni] = __builtin_amdgcn_mfma_f32_16x16x32_bf16(k2f, qfB[2], scB[ni], 0, 0, 0);
            bf16x8 k3f = *(const bf16x8*)(kO + ni * 2048 + 64);
            scA[ni] = __builtin_amdgcn_mfma_f32_16x16x32_bf16(k3f, qfA[3], scA[ni], 0, 0, 0);
            scB[ni] = __builtin_amdgcn_mfma_f32_16x16x32_bf16(k3f, qfB[3], scB[ni], 0, 0, 0);
        }
        __builtin_amdgcn_s_setprio(0);

        // ---- PV(t-1) from Vs[sP], both groups share each V fragment ----
        if (t > 0) {
            const bf16* vE = Vs + sP * 8192 + vbE;
            const bf16* vO = Vs + sP * 8192 + vbO;
            __builtin_amdgcn_s_setprio(1);
            olA = __builtin_amdgcn_mfma_f32_16x16x32_bf16(pA0, vones, olA, 0, 0, 0);
            olB = __builtin_amdgcn_mfma_f32_16x16x32_bf16(pB0, vones, olB, 0, 0, 0);
            #pragma unroll
            for (int nf = 0; nf < 8; ++nf) {
                bf16x8 v0 = *(const bf16x8*)(vE + nf * 1024);
                ofA[nf] = __builtin_amdgcn_mfma_f32_16x16x32_bf16(pA0, v0, ofA[nf], 0, 0, 0);
                ofB[nf] = __builtin_amdgcn_mfma_f32_16x16x32_bf16(pB0, v0, ofB[nf], 0, 0, 0);
            }
            olA = __builtin_amdgcn_mfma_f32_16x16x32_bf16(pA1, vones, olA, 0, 0, 0);
            olB = __builtin_amdgcn_mfma_f32_16x16x32_bf16(pB1, vones, olB, 0, 0, 0);
            #pragma unroll
            for (int nf = 0; nf < 8; ++nf) {
                bf16x8 v1 = *(const bf16x8*)(vO + nf * 1024);
                ofA[nf] = __builtin_amdgcn_mfma_f32_16x16x32_bf16(pA1, v1, ofA[nf], 0, 0, 0);
                ofB[nf] = __builtin_amdgcn_mfma_f32_16x16x32_bf16(pB1, v1, ofB[nf], 0, 0, 0);
            }
            __builtin_amdgcn_s_setprio(0);
        }

        // ---- exp2(t) + pack (VALU; interleaves with PV(t-1) MFMAs) ----
        float pa[4][4], pb[4][4];
        #pragma unroll
        for (int ni = 0; ni < 4; ++ni)
            #pragma unroll
            for (int r = 0; r < 4; ++r) {
                pa[ni][r] = __builtin_exp2f(scA[ni][r]);
                pb[ni][r] = __builtin_exp2f(scB[ni][r]);
            }
        #pragma unroll
        for (int e = 0; e < 8; ++e) {
            pA0[e] = (bf16)pa[(e >> 2)][e & 3];
            pA1[e] = (bf16)pa[2 + (e >> 2)][e & 3];
            pB0[e] = (bf16)pb[(e >> 2)][e & 3];
            pB1[e] = (bf16)pb[2 + (e >> 2)][e & 3];
        }

        __syncthreads();   // stage(t+1) drained; all waves done with Ks[buf]/Vs[sP]
        int tmp = sP; sP = sC; sC = sN; sN = tmp;
    }

    // ---- epilogue: PV(NT-1) from Vs[sP] ----
    {
        const bf16* vE = Vs + sP * 8192 + vbE;
        const bf16* vO = Vs + sP * 8192 + vbO;
        olA = __builtin_amdgcn_mfma_f32_16x16x32_bf16(pA0, vones, olA, 0, 0, 0);
        olB = __builtin_amdgcn_mfma_f32_16x16x32_bf16(pB0, vones, olB, 0, 0, 0);
        #pragma unroll
        for (int nf = 0; nf < 8; ++nf) {
            bf16x8 v0 = *(const bf16x8*)(vE + nf * 1024);
            ofA[nf] = __builtin_amdgcn_mfma_f32_16x16x32_bf16(pA0, v0, ofA[nf], 0, 0, 0);
            ofB[nf] = __builtin_amdgcn_mfma_f32_16x16x32_bf16(pB0, v0, ofB[nf], 0, 0, 0);
        }
        olA = __builtin_amdgcn_mfma_f32_16x16x32_bf16(pA1, vones, olA, 0, 0, 0);
        olB = __builtin_amdgcn_mfma_f32_16x16x32_bf16(pB1, vones, olB, 0, 0, 0);
        #pragma unroll
        for (int nf = 0; nf < 8; ++nf) {
            bf16x8 v1 = *(const bf16x8*)(vO + nf * 1024);
            ofA[nf] = __builtin_amdgcn_mfma_f32_16x16x32_bf16(pA1, v1, ofA[nf], 0, 0, 0);
            ofB[nf] = __builtin_amdgcn_mfma_f32_16x16x32_bf16(pB1, v1, ofB[nf], 0, 0, 0);
        }
    }

    // ---- normalize + store, both groups ----
    #pragma unroll
    for (int r = 0; r < 4; ++r) {
        float invA = 1.0f / olA[r];
        float invB = 1.0f / olB[r];
        size_t rowA = (size_t)(b * S + qt * 128 + w * 32 + lg * 4 + r);
        bf16* opA = O + rowA * 2048 + h * 128 + ll;
        bf16* opB = opA + 16 * 2048;
        #pragma unroll
        for (int nf = 0; nf < 8; ++nf) {
            opA[nf * 16] = (bf16)(ofA[nf][r] * invA);
            opB[nf * 16] = (bf16)(ofB[nf][r] * invB);
        }
    }
#undef STAGE
}

// ---------------- launcher ---------------------------------------------------
extern "C" void kernel_launch(void* const* d_in, const int* in_sizes, int n_in,
                              void* d_out, int out_size, void* d_ws, size_t ws_size,
                              hipStream_t stream)
{
    const float* X  = (const float*)d_in[0];
    const float* Wq = (const float*)d_in[1];
    const float* bq = (const float*)d_in[2];
    const float* Wk = (const float*)d_in[3];
    const float* bk = (const float*)d_in[4];
    const float* Wv = (const float*)d_in[5];
    const float* bv = (const float*)d_in[6];
    const float* Wo = (const float*)d_in[7];
    const float* bo = (const float*)d_in[8];
    float* out = (float*)d_out;

    // workspace layout (bf16 elements)
    bf16* p = (bf16*)d_ws;
    bf16* Xb    = p; p += 8388608;   // [4096][2048] X bf16 (reused as attn output)
    bf16* Qb    = p; p += 8388608;   // [4096][2048]
    bf16* Kbuf  = p; p += 1048576;   // [4096][256]
    bf16* VTb   = p; p += 1048576;   // [512][2048] : pi-permuted V^T
    bf16* Wqkvt = p; p += 5242880;   // [2560][2048]: Wq^T | Wk^T | Wv^T
    bf16* Wot   = p; p += 4194304;   // [2048][2048]
    float* bqkv = (float*)p; p += 5120;  // 2560 floats
    bf16* Oattn = Xb;                // alias: X dead after QKV projection

    // 1/sqrt(128) * log2(e)  (exp2-domain softmax)
    const float qscale = 0.12751744f;

    // allow 80KB dynamic LDS for attn_fwd (2 blocks/CU = 160KB exactly)
    (void)hipFuncSetAttribute((const void*)attn_fwd,
                              hipFuncAttributeMaxDynamicSharedMemorySize, 81920);

    prep<<<17418, 256, 0, stream>>>(X, Wq, Wk, Wv, Wo, bq, bk, bv,
                                    Xb, Wqkvt, Wot, bqkv);

    gemm_qkv<<<dim3(20, 32), 256, 0, stream>>>(Xb, Wqkvt, bqkv, Qb, Kbuf, VTb, qscale);

    attn_fwd<<<dim3(16, 16, 2), 256, 81920, stream>>>(Qb, Kbuf, VTb, Oattn);

    gemm_bt<0><<<dim3(16, 32), 256, 0, stream>>>(Oattn, Wot, bo, out, 4096, 2048, 2048, 1.0f);
}